// Round 3
// baseline (328.041 us; speedup 1.0000x reference)
//
#include <hip/hip_runtime.h>

#define HH 56
#define WW 56
#define HW 3136          // 56*56
#define NV4 784          // vec4 per plane; 14 vec4 per row
#define BLK 256          // 4 waves per block
#define CPB 4            // one channel per wave

typedef float f4 __attribute__((ext_vector_type(4)));   // native clang vector for nontemporal builtins

__global__ __launch_bounds__(BLK) void local_mask_kernel(
    const float* __restrict__ x, const int* __restrict__ T, float* __restrict__ out,
    int channels)
{
    const int wave = threadIdx.x >> 6;
    const int lane = threadIdx.x & 63;
    const int ch   = blockIdx.x * CPB + wave;
    if (ch >= channels) return;

    // Wave-uniform mark flag; resolves the branch early.
    const bool marked = (T[ch] > 0);

    const f4* __restrict__ xin  = (const f4*)(x   + (size_t)ch * HW);
    f4* __restrict__       xout = (f4*)      (out + (size_t)ch * HW);

    // One wave owns the whole plane: 784 vec4 = 12 full rounds + 16-lane tail.
    // Streaming data, zero reuse -> nontemporal loads/stores.
    const bool tail = (lane < 16);
    f4 v[13];
    #pragma unroll
    for (int k = 0; k < 12; ++k)
        v[k] = __builtin_nontemporal_load(&xin[lane + k * 64]);
    if (tail)
        v[12] = __builtin_nontemporal_load(&xin[lane + 768]);

    if (!marked) {
        // Straight copy. No barriers anywhere: divergent wave exit is fine.
        #pragma unroll
        for (int k = 0; k < 12; ++k)
            __builtin_nontemporal_store(v[k], &xout[lane + k * 64]);
        if (tail)
            __builtin_nontemporal_store(v[12], &xout[lane + 768]);
        return;
    }

    // ---- per-lane argmax (ascending indices => first-index tie-break) ----
    float bestv = -__builtin_inff();
    int   besti = 0;
    #pragma unroll
    for (int k = 0; k < 13; ++k) {
        if (k < 12 || tail) {
            const int i    = lane + k * 64;
            const f4  f    = v[k];
            const int base = i * 4;
            if (f.x > bestv) { bestv = f.x; besti = base;     }
            if (f.y > bestv) { bestv = f.y; besti = base + 1; }
            if (f.z > bestv) { bestv = f.z; besti = base + 2; }
            if (f.w > bestv) { bestv = f.w; besti = base + 3; }
        }
    }

    // ---- wave64 reduction, lexicographic (val desc, idx asc) ----
    // Purely intra-wave: no LDS, no __syncthreads, no cross-wave coupling.
    #pragma unroll
    for (int off = 32; off > 0; off >>= 1) {
        float ov = __shfl_down(bestv, (unsigned)off);
        int   oi = __shfl_down(besti, (unsigned)off);
        if (ov > bestv || (ov == bestv && oi < besti)) { bestv = ov; besti = oi; }
    }
    // Broadcast lane 0's winner to all lanes.
    const int bi = __shfl(besti, 0);

    // ---- box + lam (every lane redundantly; cheap scalar math) ----
    const int mi = bi / HH;
    const int mj = bi - mi * HH;          // ref uses H for both div and mod
    const int h1 = max(mi - 3, 0);
    const int h2 = min(mi + 3, HH - 1);
    const int w1 = max(mj - 3, 0);
    const int w2 = min(mj + 3, WW - 1);
    const int zeros = (h2 - h1) * (w2 - w1);   // box is [h1,h2) x [w1,w2)
    const float lam = (float)HW / (float)(HW - zeros);

    // ---- write: in-box -> 0, else x*lam.
    // WW=56 -> 14 vec4 per row: a vec4 never crosses a row boundary.
    #pragma unroll
    for (int k = 0; k < 13; ++k) {
        if (k < 12 || tail) {
            const int i    = lane + k * 64;
            const f4  f    = v[k];
            const int row  = i / 14;               // const div -> magic mul
            const int col0 = (i - row * 14) * 4;
            const bool rin = (row >= h1) & (row < h2);
            f4 o;
            o.x = (rin & (col0     >= w1) & (col0     < w2)) ? 0.0f : f.x * lam;
            o.y = (rin & (col0 + 1 >= w1) & (col0 + 1 < w2)) ? 0.0f : f.y * lam;
            o.z = (rin & (col0 + 2 >= w1) & (col0 + 2 < w2)) ? 0.0f : f.z * lam;
            o.w = (rin & (col0 + 3 >= w1) & (col0 + 3 < w2)) ? 0.0f : f.w * lam;
            __builtin_nontemporal_store(o, &xout[i]);
        }
    }
}

extern "C" void kernel_launch(void* const* d_in, const int* in_sizes, int n_in,
                              void* d_out, int out_size, void* d_ws, size_t ws_size,
                              hipStream_t stream) {
    const float* x = (const float*)d_in[0];
    const int*   T = (const int*)d_in[1];
    float*     out = (float*)d_out;
    const int channels = in_sizes[0] / HW;   // B*C = 16384
    const int blocks = (channels + CPB - 1) / CPB;
    local_mask_kernel<<<blocks, BLK, 0, stream>>>(x, T, out, channels);
}

// Round 4
// 323.761 us; speedup vs baseline: 1.0132x; 1.0132x over previous
//
#include <hip/hip_runtime.h>

#define HH 56
#define WW 56
#define HW 3136          // 56*56
#define NV4 784          // vec4 per plane; 14 vec4 per row
#define BLK 256

typedef float f4 __attribute__((ext_vector_type(4)));   // native clang vector for nontemporal builtins

// launch_bounds(256, 8): 8 waves/SIMD min occupancy -> caps VGPR at 64.
// Payload is only v[4] = 16 VGPRs + ~24 scalars/temps, fits comfortably.
__global__ __launch_bounds__(BLK, 8) void local_mask_kernel(
    const float* __restrict__ x, const int* __restrict__ T, float* __restrict__ out)
{
    const int ch  = blockIdx.x;
    const int tid = threadIdx.x;

    // Block-uniform mark flag (scalar load), issued before the vector stream.
    const bool marked = (T[ch] > 0);

    const f4* __restrict__ xin  = (const f4*)(x   + (size_t)ch * HW);
    f4* __restrict__       xout = (f4*)      (out + (size_t)ch * HW);

    // Load the whole plane into registers: 784 vec4 over 256 threads
    // (threads 0..15 take a 4th vec4). Streaming, zero reuse -> nt loads.
    f4 v[4];
    #pragma unroll
    for (int k = 0; k < 4; ++k) {
        int i = tid + k * BLK;
        if (i < NV4) v[k] = __builtin_nontemporal_load(&xin[i]);
    }

    if (!marked) {
        // Straight copy with nt stores; compiler hoists loads and counts vmcnt.
        #pragma unroll
        for (int k = 0; k < 4; ++k) {
            int i = tid + k * BLK;
            if (i < NV4) __builtin_nontemporal_store(v[k], &xout[i]);
        }
        return;
    }

    // ---- per-thread argmax (ascending indices => first-index tie-break) ----
    float bestv = -__builtin_inff();
    int   besti = 0;
    #pragma unroll
    for (int k = 0; k < 4; ++k) {
        int i = tid + k * BLK;
        if (i < NV4) {
            const f4 f = v[k];
            const int base = i * 4;
            if (f.x > bestv) { bestv = f.x; besti = base;     }
            if (f.y > bestv) { bestv = f.y; besti = base + 1; }
            if (f.z > bestv) { bestv = f.z; besti = base + 2; }
            if (f.w > bestv) { bestv = f.w; besti = base + 3; }
        }
    }

    // ---- wave64 reduction, lexicographic (val desc, idx asc) ----
    #pragma unroll
    for (int off = 32; off > 0; off >>= 1) {
        float ov = __shfl_down(bestv, (unsigned)off);
        int   oi = __shfl_down(besti, (unsigned)off);
        if (ov > bestv || (ov == bestv && oi < besti)) { bestv = ov; besti = oi; }
    }

    // ---- cross-wave (4 waves) via LDS: ONE barrier, then every thread
    //      redundantly reduces the 4 candidates (broadcast reads, no conflict).
    __shared__ float s_v[4];
    __shared__ int   s_i[4];

    const int wave = tid >> 6;
    const int lane = tid & 63;
    if (lane == 0) { s_v[wave] = bestv; s_i[wave] = besti; }
    __syncthreads();

    float bv = s_v[0]; int bi = s_i[0];
    #pragma unroll
    for (int w = 1; w < 4; ++w) {
        const float wv = s_v[w]; const int wi = s_i[w];
        if (wv > bv || (wv == bv && wi < bi)) { bv = wv; bi = wi; }
    }

    const int mi = bi / HH;
    const int mj = bi - mi * HH;          // ref uses H for both div and mod
    const int h1 = max(mi - 3, 0);
    const int h2 = min(mi + 3, HH - 1);
    const int w1 = max(mj - 3, 0);
    const int w2 = min(mj + 3, WW - 1);
    const int zeros = (h2 - h1) * (w2 - w1);   // box is [h1,h2) x [w1,w2)
    const float lam = (float)HW / (float)(HW - zeros);

    // ---- write: in-box -> 0, else x*lam.
    // WW=56 -> 14 vec4 per row: a vec4 never crosses a row boundary.
    // One i/14 per vector instead of four e/56 magic-muls.
    #pragma unroll
    for (int k = 0; k < 4; ++k) {
        int i = tid + k * BLK;
        if (i < NV4) {
            const f4  f    = v[k];
            const int row  = i / 14;               // const div -> magic mul
            const int col0 = (i - row * 14) * 4;
            const bool rin = (row >= h1) & (row < h2);
            f4 o;
            o.x = (rin & (col0     >= w1) & (col0     < w2)) ? 0.0f : f.x * lam;
            o.y = (rin & (col0 + 1 >= w1) & (col0 + 1 < w2)) ? 0.0f : f.y * lam;
            o.z = (rin & (col0 + 2 >= w1) & (col0 + 2 < w2)) ? 0.0f : f.z * lam;
            o.w = (rin & (col0 + 3 >= w1) & (col0 + 3 < w2)) ? 0.0f : f.w * lam;
            __builtin_nontemporal_store(o, &xout[i]);
        }
    }
}

extern "C" void kernel_launch(void* const* d_in, const int* in_sizes, int n_in,
                              void* d_out, int out_size, void* d_ws, size_t ws_size,
                              hipStream_t stream) {
    const float* x = (const float*)d_in[0];
    const int*   T = (const int*)d_in[1];
    float*     out = (float*)d_out;
    const int channels = in_sizes[0] / HW;   // B*C = 16384
    local_mask_kernel<<<channels, BLK, 0, stream>>>(x, T, out);
}